// Round 2
// baseline (634.392 us; speedup 1.0000x reference)
//
#include <hip/hip_runtime.h>

static constexpr int NN = 100000;
static constexpr int NE = 1600000;
static constexpr int NB_SCAN = (NN + 1023) / 1024;   // 98

typedef __bf16 bf16x8 __attribute__((ext_vector_type(8)));
typedef float  f32x4  __attribute__((ext_vector_type(4)));

__device__ __forceinline__ unsigned short f2b(float f){
  unsigned u = __builtin_bit_cast(unsigned, f);
  u += 0x7fffu + ((u >> 16) & 1u);          // round-to-nearest-even
  return (unsigned short)(u >> 16);
}
__device__ __forceinline__ float b2f(unsigned short b){
  return __builtin_bit_cast(float, (unsigned)b << 16);
}

// split f32 -> (hi, lo) bf16 pair: v ~= hi + lo with ~16-bit mantissa coverage
__device__ __forceinline__ void split1(float v, __bf16& h, __bf16& l){
  unsigned short hb = f2b(v);
  float hf = b2f(hb);
  h = __builtin_bit_cast(__bf16, hb);
  l = __builtin_bit_cast(__bf16, f2b(v - hf));
}

__device__ __forceinline__ void split8(const float* __restrict__ p, bf16x8& h, bf16x8& l){
  #pragma unroll
  for (int j=0;j<8;j++){
    __bf16 hh, ll; split1(p[j], hh, ll); h[j] = hh; l[j] = ll;
  }
}

// ---------------- weight packing into MFMA B-fragment order (hi + lo) ----------------
// frag f=(kt*NCT+ct): lane holds B[kt*32+(lane>>4)*8+j][ct*16+(lane&15)], j=0..7
__global__ void k_pack(const float* __restrict__ w11, const float* __restrict__ w12,
                       const float* __restrict__ w21, const float* __restrict__ w22,
                       const float* __restrict__ wm1, const float* __restrict__ wm2,
                       unsigned short* __restrict__ p11h, unsigned short* __restrict__ p11l,
                       unsigned short* __restrict__ p12h, unsigned short* __restrict__ p12l,
                       unsigned short* __restrict__ p21h, unsigned short* __restrict__ p21l,
                       unsigned short* __restrict__ p22h, unsigned short* __restrict__ p22l,
                       unsigned short* __restrict__ pm1h, unsigned short* __restrict__ pm1l,
                       unsigned short* __restrict__ pm2h, unsigned short* __restrict__ pm2l){
  int b = blockIdx.x, lane = threadIdx.x;
  const float* W; unsigned short* Ph; unsigned short* Pl; int NCT, f;
  if (b < 160){
    int m = b >> 5; f = b & 31; NCT = 8;
    W  = (m==0)?w11 :(m==1)?w12 :(m==2)?w21 :(m==3)?w22 :wm1;
    Ph = (m==0)?p11h:(m==1)?p12h:(m==2)?p21h:(m==3)?p22h:pm1h;
    Pl = (m==0)?p11l:(m==1)?p12l:(m==2)?p21l:(m==3)?p22l:pm1l;
  } else { f = b - 160; NCT = 4; W = wm2; Ph = pm2h; Pl = pm2l; }
  int NC = NCT * 16;
  int kt = f / NCT, ct = f % NCT;
  int k0 = kt*32 + ((lane>>4)*8), col = ct*16 + (lane&15);
  unsigned short* dh = Ph + ((size_t)(f*64 + lane))*8;
  unsigned short* dl = Pl + ((size_t)(f*64 + lane))*8;
  #pragma unroll
  for (int j=0;j<8;j++){
    float v = W[(size_t)(k0+j)*NC + col];
    unsigned short hb = f2b(v);
    dh[j] = hb;
    dl[j] = f2b(v - b2f(hb));
  }
}

// ---------------- CSR build ----------------
__global__ void k_count(const int* __restrict__ dst, int* __restrict__ deg, int E){
  int t = blockIdx.x*256 + threadIdx.x;
  if (t < E) atomicAdd(&deg[dst[t]], 1);
}

__global__ void k_bsum(const int* __restrict__ deg, int* __restrict__ bsum, int N){
  __shared__ int s[256];
  int b = blockIdx.x, t = threadIdx.x;
  int base = b*1024 + t*4, sum = 0;
  #pragma unroll
  for (int j=0;j<4;j++){ int idx = base + j; if (idx < N) sum += deg[idx]; }
  s[t] = sum; __syncthreads();
  for (int off=128; off; off>>=1){ if (t < off) s[t] += s[t+off]; __syncthreads(); }
  if (t == 0) bsum[b] = s[0];
}

__global__ void k_boff(const int* __restrict__ bsum, int* __restrict__ boff, int nb){
  if (threadIdx.x == 0){
    int r = 0;
    for (int b=0;b<nb;b++){ boff[b] = r; r += bsum[b]; }
  }
}

__global__ void k_scan3(const int* __restrict__ deg, const int* __restrict__ boff,
                        int* __restrict__ rs, int N){
  __shared__ int s[256];
  int b = blockIdx.x, t = threadIdx.x;
  int base = b*1024 + t*4;
  int loc[4]; int sum = 0;
  #pragma unroll
  for (int j=0;j<4;j++){ int idx = base + j; loc[j] = (idx < N) ? deg[idx] : 0; sum += loc[j]; }
  s[t] = sum; __syncthreads();
  for (int off=1; off<256; off<<=1){
    int v = 0; if (t >= off) v = s[t-off];
    __syncthreads(); s[t] += v; __syncthreads();
  }
  int run = boff[b] + s[t] - sum;   // exclusive prefix
  #pragma unroll
  for (int j=0;j<4;j++){ int idx = base + j; if (idx < N) rs[idx] = run; run += loc[j]; }
}

__global__ void k_fill(const int* __restrict__ src, const int* __restrict__ dst,
                       const int* __restrict__ rs, int* __restrict__ cur,
                       int* __restrict__ eidx, int E){
  int t = blockIdx.x*256 + threadIdx.x;
  if (t < E){
    int d = dst[t];
    int pos = atomicAdd(&cur[d], 1);
    eidx[rs[d] + pos] = src[t];
  }
}

// -------- aggregation (f32): out = (1+eps)*in + sum_{nbr} in[nbr], rows of 128 f32 ----
__global__ __launch_bounds__(256) void k_agg(const float* __restrict__ in,
                                             float* __restrict__ out,
                                             const float* __restrict__ epsp,
                                             const int* __restrict__ rs, const int* __restrict__ deg,
                                             const int* __restrict__ eidx, int N){
  int gw = (blockIdx.x*256 + threadIdx.x) >> 6;
  int lane = threadIdx.x & 63;
  if (gw >= N) return;
  float sc = 1.0f + *epsp;
  const float2* inp = reinterpret_cast<const float2*>(in);
  float2 v = inp[(size_t)gw*64 + lane];
  float a0 = sc * v.x, a1 = sc * v.y;
  int beg = rs[gw], d = deg[gw];
  for (int i=0;i<d;i++){
    int s = eidx[beg + i];
    float2 u = inp[(size_t)s*64 + lane];
    a0 += u.x; a1 += u.y;
  }
  reinterpret_cast<float2*>(out)[(size_t)gw*64 + lane] = make_float2(a0, a1);
}

// ---------------- MFMA helpers ----------------
// A frag: row = lane&15, k = (lane>>4)*8 + j ; D: col = lane&15, row = (lane>>4)*4 + r
__device__ __forceinline__ void load_a_glob(const float* __restrict__ t, int rbase,
                                            int wv, int lane, int N,
                                            bf16x8 ah[4], bf16x8 al[4]){
  int row = rbase + wv*16 + (lane & 15); if (row >= N) row = N - 1;
  const float* ap = t + (size_t)row*128 + ((lane>>4)*8);
  #pragma unroll
  for (int kt=0;kt<4;kt++) split8(ap + kt*32, ah[kt], al[kt]);
}
// LDS f32 tile with row stride `stride` (in floats)
__device__ __forceinline__ void load_a_lds(const float* base, int lane,
                                           bf16x8 ah[4], bf16x8 al[4], int stride){
  int row = lane & 15, ko = (lane>>4)*8;
  #pragma unroll
  for (int kt=0;kt<4;kt++) split8(base + row*stride + kt*32 + ko, ah[kt], al[kt]);
}

template<int NCT>
__device__ __forceinline__ void mm_stage3(const bf16x8 ah[4], const bf16x8 al[4],
                                          const unsigned short* __restrict__ wh,
                                          const unsigned short* __restrict__ wl,
                                          int lane, f32x4 acc[NCT]){
  #pragma unroll
  for (int ct=0; ct<NCT; ++ct){
    f32x4 c = {0.f,0.f,0.f,0.f};
    #pragma unroll
    for (int kt=0; kt<4; ++kt){
      int fo = ((kt*NCT + ct)*64 + lane) << 3;
      bf16x8 bh = *reinterpret_cast<const bf16x8*>(wh + fo);
      bf16x8 bl = *reinterpret_cast<const bf16x8*>(wl + fo);
      c = __builtin_amdgcn_mfma_f32_16x16x32_bf16(ah[kt], bh, c, 0, 0, 0);
      c = __builtin_amdgcn_mfma_f32_16x16x32_bf16(al[kt], bh, c, 0, 0, 0);
      c = __builtin_amdgcn_mfma_f32_16x16x32_bf16(ah[kt], bl, c, 0, 0, 0);
    }
    acc[ct] = c;
  }
}

// bias + relu -> f32 LDS tile (row stride `stride` floats)
template<int NCT>
__device__ __forceinline__ void epi_relu_lds(const f32x4 acc[NCT], const float* __restrict__ bias,
                                             float* dst, int lane, int stride){
  int r0 = (lane>>4)*4, col0 = lane & 15;
  #pragma unroll
  for (int ct=0; ct<NCT; ++ct){
    float bv = bias[ct*16 + col0];
    #pragma unroll
    for (int r=0;r<4;r++){
      float v = fmaxf(acc[ct][r] + bv, 0.f);
      dst[(r0 + r)*stride + ct*16 + col0] = v;
    }
  }
}

static constexpr int LSTR = 132;   // f32 row stride in LDS (pad 4 -> 2-way banks, 16B aligned)

// ---------------- layer-1 MLP: h1 = relu(relu(t@w1+b1)@w2+b2) ----------------
__global__ __launch_bounds__(256) void k_mlp1(const float* __restrict__ t,
    const unsigned short* __restrict__ w1h, const unsigned short* __restrict__ w1l, const float* __restrict__ b1,
    const unsigned short* __restrict__ w2h, const unsigned short* __restrict__ w2l, const float* __restrict__ b2,
    float* __restrict__ h, int N){
  __shared__ float lds[64*LSTR];
  int tid = threadIdx.x, lane = tid & 63, wv = tid >> 6;
  int rbase = blockIdx.x * 64;
  bf16x8 ah[4], al[4];
  f32x4 acc[8];
  load_a_glob(t, rbase, wv, lane, N, ah, al);
  mm_stage3<8>(ah, al, w1h, w1l, lane, acc);
  epi_relu_lds<8>(acc, b1, lds + wv*16*LSTR, lane, LSTR);
  __syncthreads();
  load_a_lds(lds + wv*16*LSTR, lane, ah, al, LSTR);
  __syncthreads();
  mm_stage3<8>(ah, al, w2h, w2l, lane, acc);
  epi_relu_lds<8>(acc, b2, lds + wv*16*LSTR, lane, LSTR);
  __syncthreads();
  int nvalid = N - rbase; if (nvalid > 64) nvalid = 64;
  float4* dv = reinterpret_cast<float4*>(h + (size_t)rbase*128);
  for (int i=tid; i < nvalid*32; i += 256){
    int row = i >> 5, c4 = i & 31;
    dv[i] = *reinterpret_cast<const float4*>(&lds[row*LSTR + c4*4]);
  }
}

// ------------- layer-2 MLP + head fused: out = sigmoid(mlp_head(relu(mlp2(t2)))) -------------
__global__ __launch_bounds__(256) void k_mlp2_head(const float* __restrict__ t,
    const unsigned short* __restrict__ w1h, const unsigned short* __restrict__ w1l, const float* __restrict__ b1,
    const unsigned short* __restrict__ w2h, const unsigned short* __restrict__ w2l, const float* __restrict__ b2,
    const unsigned short* __restrict__ w3h, const unsigned short* __restrict__ w3l, const float* __restrict__ b3,
    const unsigned short* __restrict__ w4h, const unsigned short* __restrict__ w4l, const float* __restrict__ b4,
    float* __restrict__ out, int N){
  __shared__ float lds[64*LSTR];
  int tid = threadIdx.x, lane = tid & 63, wv = tid >> 6;
  int rbase = blockIdx.x * 64;
  bf16x8 ah[4], al[4];
  f32x4 acc[8];
  // stage1: u2 = relu(t@w21+b21)
  load_a_glob(t, rbase, wv, lane, N, ah, al);
  mm_stage3<8>(ah, al, w1h, w1l, lane, acc);
  epi_relu_lds<8>(acc, b1, lds + wv*16*LSTR, lane, LSTR);
  __syncthreads();
  // stage2: h2 = relu(u2@w22+b22)
  load_a_lds(lds + wv*16*LSTR, lane, ah, al, LSTR);
  __syncthreads();
  mm_stage3<8>(ah, al, w2h, w2l, lane, acc);
  epi_relu_lds<8>(acc, b2, lds + wv*16*LSTR, lane, LSTR);
  __syncthreads();
  // stage3: uh = relu(h2@wm1+bm1)
  load_a_lds(lds + wv*16*LSTR, lane, ah, al, LSTR);
  __syncthreads();
  mm_stage3<8>(ah, al, w3h, w3l, lane, acc);
  epi_relu_lds<8>(acc, b3, lds + wv*16*LSTR, lane, LSTR);
  __syncthreads();
  // stage4: out = sigmoid(uh@wm2+bm2), 64 cols
  load_a_lds(lds + wv*16*LSTR, lane, ah, al, LSTR);
  __syncthreads();
  f32x4 acc4[4];
  mm_stage3<4>(ah, al, w4h, w4l, lane, acc4);
  {
    float* olds = lds;   // reuse as [64][68] f32
    int r0 = (lane>>4)*4, col0 = lane & 15;
    #pragma unroll
    for (int ct=0; ct<4; ++ct){
      float bv = b4[ct*16 + col0];
      #pragma unroll
      for (int r=0;r<4;r++){
        float z = acc4[ct][r] + bv;
        float s = 1.0f / (1.0f + __expf(-z));
        olds[(wv*16 + r0 + r)*68 + ct*16 + col0] = s;
      }
    }
  }
  __syncthreads();
  int nvalid = N - rbase; if (nvalid > 64) nvalid = 64;
  float4* dv = reinterpret_cast<float4*>(out + (size_t)rbase*64);
  for (int i=tid; i < nvalid*16; i += 256){
    int row = i >> 4, c4 = i & 15;
    dv[i] = *reinterpret_cast<const float4*>(&lds[row*68 + c4*4]);
  }
}

// ---------------- host launch ----------------
extern "C" void kernel_launch(void* const* d_in, const int* in_sizes, int n_in,
                              void* d_out, int out_size, void* d_ws, size_t ws_size,
                              hipStream_t stream) {
  const float* x   = (const float*)d_in[0];
  const int*   src = (const int*)  d_in[1];
  const int*   dst = (const int*)  d_in[2];
  const float* eps1= (const float*)d_in[3];
  const float* eps2= (const float*)d_in[4];
  const float* w11 = (const float*)d_in[5];  const float* b11 = (const float*)d_in[6];
  const float* w12 = (const float*)d_in[7];  const float* b12 = (const float*)d_in[8];
  const float* w21 = (const float*)d_in[9];  const float* b21 = (const float*)d_in[10];
  const float* w22 = (const float*)d_in[11]; const float* b22 = (const float*)d_in[12];
  const float* wm1 = (const float*)d_in[13]; const float* bm1 = (const float*)d_in[14];
  const float* wm2 = (const float*)d_in[15]; const float* bm2 = (const float*)d_in[16];

  char* ws = (char*)d_ws;
  size_t off = 0;
  auto alloc = [&](size_t bytes) -> void* {
    void* p = ws + off;
    off = (off + bytes + 255) & ~(size_t)255;
    return p;
  };
  float* B0 = (float*)alloc((size_t)NN*128*4);   // agg output (t1 / t2)
  float* B1 = (float*)alloc((size_t)NN*128*4);   // h1
  int* eidx = (int*)alloc((size_t)NE*4);
  int* deg  = (int*)alloc((size_t)NN*4);
  int* cur  = (int*)alloc((size_t)NN*4);
  int* rs   = (int*)alloc((size_t)NN*4);
  int* bsum = (int*)alloc((size_t)NB_SCAN*4);
  int* boff = (int*)alloc((size_t)NB_SCAN*4);
  unsigned short* p11h = (unsigned short*)alloc(128*128*2);
  unsigned short* p11l = (unsigned short*)alloc(128*128*2);
  unsigned short* p12h = (unsigned short*)alloc(128*128*2);
  unsigned short* p12l = (unsigned short*)alloc(128*128*2);
  unsigned short* p21h = (unsigned short*)alloc(128*128*2);
  unsigned short* p21l = (unsigned short*)alloc(128*128*2);
  unsigned short* p22h = (unsigned short*)alloc(128*128*2);
  unsigned short* p22l = (unsigned short*)alloc(128*128*2);
  unsigned short* pm1h = (unsigned short*)alloc(128*128*2);
  unsigned short* pm1l = (unsigned short*)alloc(128*128*2);
  unsigned short* pm2h = (unsigned short*)alloc(128*64*2);
  unsigned short* pm2l = (unsigned short*)alloc(128*64*2);
  if (off > ws_size) return;   // visible failure if workspace too small

  hipMemsetAsync(deg, 0, (size_t)NN*4, stream);
  hipMemsetAsync(cur, 0, (size_t)NN*4, stream);

  k_pack<<<176, 64, 0, stream>>>(w11,w12,w21,w22,wm1,wm2,
                                 p11h,p11l,p12h,p12l,p21h,p21l,p22h,p22l,pm1h,pm1l,pm2h,pm2l);
  k_count<<<(NE+255)/256, 256, 0, stream>>>(dst, deg, NE);
  k_bsum<<<NB_SCAN, 256, 0, stream>>>(deg, bsum, NN);
  k_boff<<<1, 64, 0, stream>>>(bsum, boff, NB_SCAN);
  k_scan3<<<NB_SCAN, 256, 0, stream>>>(deg, boff, rs, NN);
  k_fill<<<(NE+255)/256, 256, 0, stream>>>(src, dst, rs, cur, eidx, NE);

  // layer 1
  k_agg<<<(NN+3)/4, 256, 0, stream>>>(x, B0, eps1, rs, deg, eidx, NN);
  k_mlp1<<<(NN+63)/64, 256, 0, stream>>>(B0, p11h, p11l, b11, p12h, p12l, b12, B1, NN);
  // layer 2 + head
  k_agg<<<(NN+3)/4, 256, 0, stream>>>(B1, B0, eps2, rs, deg, eidx, NN);
  k_mlp2_head<<<(NN+63)/64, 256, 0, stream>>>(B0, p21h, p21l, b21, p22h, p22l, b22,
                                              pm1h, pm1l, bm1, pm2h, pm2l, bm2,
                                              (float*)d_out, NN);
}

// Round 3
// 458.353 us; speedup vs baseline: 1.3841x; 1.3841x over previous
//
#include <hip/hip_runtime.h>

static constexpr int NN = 100000;
static constexpr int NE = 1600000;
static constexpr int NB_SCAN = (NN + 1023) / 1024;   // 98

typedef __bf16    bf16x8 __attribute__((ext_vector_type(8)));
typedef float     f32x4  __attribute__((ext_vector_type(4)));
typedef _Float16  f16x8  __attribute__((ext_vector_type(8)));

__device__ __forceinline__ unsigned short f2b(float f){
  unsigned u = __builtin_bit_cast(unsigned, f);
  u += 0x7fffu + ((u >> 16) & 1u);          // round-to-nearest-even
  return (unsigned short)(u >> 16);
}
__device__ __forceinline__ float b2f(unsigned short b){
  return __builtin_bit_cast(float, (unsigned)b << 16);
}

// split f32 -> (hi, lo) bf16 pair: v ~= hi + lo with ~16-bit mantissa coverage
__device__ __forceinline__ void split1(float v, __bf16& h, __bf16& l){
  unsigned short hb = f2b(v);
  float hf = b2f(hb);
  h = __builtin_bit_cast(__bf16, hb);
  l = __builtin_bit_cast(__bf16, f2b(v - hf));
}

__device__ __forceinline__ void split8f(const float* __restrict__ p, bf16x8& h, bf16x8& l){
  #pragma unroll
  for (int j=0;j<8;j++){
    __bf16 hh, ll; split1(p[j], hh, ll); h[j] = hh; l[j] = ll;
  }
}
__device__ __forceinline__ void split8h(f16x8 v, bf16x8& h, bf16x8& l){
  #pragma unroll
  for (int j=0;j<8;j++){
    __bf16 hh, ll; split1((float)v[j], hh, ll); h[j] = hh; l[j] = ll;
  }
}

// fp16 pack/unpack (2 elems per 32-bit word)
__device__ __forceinline__ unsigned pkh(float x, float y){
  unsigned short a = __builtin_bit_cast(unsigned short, (_Float16)x);
  unsigned short b = __builtin_bit_cast(unsigned short, (_Float16)y);
  return (unsigned)a | ((unsigned)b << 16);
}
__device__ __forceinline__ float2 uph(unsigned u){
  _Float16 a = __builtin_bit_cast(_Float16, (unsigned short)(u & 0xffffu));
  _Float16 b = __builtin_bit_cast(_Float16, (unsigned short)(u >> 16));
  return make_float2((float)a, (float)b);
}

// ---------------- weight packing into MFMA B-fragment order (hi + lo) ----------------
// frag f=(kt*NCT+ct): lane holds B[kt*32+(lane>>4)*8+j][ct*16+(lane&15)], j=0..7
__global__ void k_pack(const float* __restrict__ w11, const float* __restrict__ w12,
                       const float* __restrict__ w21, const float* __restrict__ w22,
                       const float* __restrict__ wm1, const float* __restrict__ wm2,
                       unsigned short* __restrict__ p11h, unsigned short* __restrict__ p11l,
                       unsigned short* __restrict__ p12h, unsigned short* __restrict__ p12l,
                       unsigned short* __restrict__ p21h, unsigned short* __restrict__ p21l,
                       unsigned short* __restrict__ p22h, unsigned short* __restrict__ p22l,
                       unsigned short* __restrict__ pm1h, unsigned short* __restrict__ pm1l,
                       unsigned short* __restrict__ pm2h, unsigned short* __restrict__ pm2l){
  int b = blockIdx.x, lane = threadIdx.x;
  const float* W; unsigned short* Ph; unsigned short* Pl; int NCT, f;
  if (b < 160){
    int m = b >> 5; f = b & 31; NCT = 8;
    W  = (m==0)?w11 :(m==1)?w12 :(m==2)?w21 :(m==3)?w22 :wm1;
    Ph = (m==0)?p11h:(m==1)?p12h:(m==2)?p21h:(m==3)?p22h:pm1h;
    Pl = (m==0)?p11l:(m==1)?p12l:(m==2)?p21l:(m==3)?p22l:pm1l;
  } else { f = b - 160; NCT = 4; W = wm2; Ph = pm2h; Pl = pm2l; }
  int NC = NCT * 16;
  int kt = f / NCT, ct = f % NCT;
  int k0 = kt*32 + ((lane>>4)*8), col = ct*16 + (lane&15);
  unsigned short* dh = Ph + ((size_t)(f*64 + lane))*8;
  unsigned short* dl = Pl + ((size_t)(f*64 + lane))*8;
  #pragma unroll
  for (int j=0;j<8;j++){
    float v = W[(size_t)(k0+j)*NC + col];
    unsigned short hb = f2b(v);
    dh[j] = hb;
    dl[j] = f2b(v - b2f(hb));
  }
}

// ---------------- f32 -> fp16 convert ----------------
__global__ void k_cvt(const float* __restrict__ x, unsigned* __restrict__ xh, int n4){
  int i = blockIdx.x*256 + threadIdx.x;
  if (i < n4){
    float4 v = reinterpret_cast<const float4*>(x)[i];
    uint2 o; o.x = pkh(v.x, v.y); o.y = pkh(v.z, v.w);
    reinterpret_cast<uint2*>(xh)[i] = o;
  }
}

// ---------------- CSR build ----------------
__global__ void k_count(const int* __restrict__ dst, int* __restrict__ deg, int E){
  int t = blockIdx.x*256 + threadIdx.x;
  if (t < E) atomicAdd(&deg[dst[t]], 1);
}

__global__ void k_bsum(const int* __restrict__ deg, int* __restrict__ bsum, int N){
  __shared__ int s[256];
  int b = blockIdx.x, t = threadIdx.x;
  int base = b*1024 + t*4, sum = 0;
  #pragma unroll
  for (int j=0;j<4;j++){ int idx = base + j; if (idx < N) sum += deg[idx]; }
  s[t] = sum; __syncthreads();
  for (int off=128; off; off>>=1){ if (t < off) s[t] += s[t+off]; __syncthreads(); }
  if (t == 0) bsum[b] = s[0];
}

__global__ void k_boff(const int* __restrict__ bsum, int* __restrict__ boff, int nb){
  if (threadIdx.x == 0){
    int r = 0;
    for (int b=0;b<nb;b++){ boff[b] = r; r += bsum[b]; }
  }
}

__global__ void k_scan3(const int* __restrict__ deg, const int* __restrict__ boff,
                        int* __restrict__ rs, int N){
  __shared__ int s[256];
  int b = blockIdx.x, t = threadIdx.x;
  int base = b*1024 + t*4;
  int loc[4]; int sum = 0;
  #pragma unroll
  for (int j=0;j<4;j++){ int idx = base + j; loc[j] = (idx < N) ? deg[idx] : 0; sum += loc[j]; }
  s[t] = sum; __syncthreads();
  for (int off=1; off<256; off<<=1){
    int v = 0; if (t >= off) v = s[t-off];
    __syncthreads(); s[t] += v; __syncthreads();
  }
  int run = boff[b] + s[t] - sum;   // exclusive prefix
  #pragma unroll
  for (int j=0;j<4;j++){ int idx = base + j; if (idx < N) rs[idx] = run; run += loc[j]; }
}

__global__ void k_fill(const int* __restrict__ src, const int* __restrict__ dst,
                       const int* __restrict__ rs, int* __restrict__ cur,
                       int* __restrict__ eidx, int E){
  int t = blockIdx.x*256 + threadIdx.x;
  if (t < E){
    int d = dst[t];
    int pos = atomicAdd(&cur[d], 1);
    eidx[rs[d] + pos] = src[t];
  }
}

// ---- aggregation (fp16 rows, f32 accum): out = (1+eps)*in + sum_{nbr} in[nbr] ----
__global__ __launch_bounds__(256) void k_agg(const unsigned* __restrict__ inp,
                                             unsigned* __restrict__ out,
                                             const float* __restrict__ epsp,
                                             const int* __restrict__ rs, const int* __restrict__ deg,
                                             const int* __restrict__ eidx, int N){
  int gw = (blockIdx.x*256 + threadIdx.x) >> 6;
  int lane = threadIdx.x & 63;
  if (gw >= N) return;
  float sc = 1.0f + *epsp;
  float2 v = uph(inp[(size_t)gw*64 + lane]);
  float a0 = sc * v.x, a1 = sc * v.y;
  int beg = rs[gw], d = deg[gw];
  int i = 0;
  for (; i+4 <= d; i += 4){
    int s0 = eidx[beg+i], s1 = eidx[beg+i+1], s2 = eidx[beg+i+2], s3 = eidx[beg+i+3];
    unsigned u0 = inp[(size_t)s0*64 + lane];
    unsigned u1 = inp[(size_t)s1*64 + lane];
    unsigned u2 = inp[(size_t)s2*64 + lane];
    unsigned u3 = inp[(size_t)s3*64 + lane];
    float2 f0 = uph(u0), f1 = uph(u1), f2 = uph(u2), f3 = uph(u3);
    a0 += (f0.x + f1.x) + (f2.x + f3.x);
    a1 += (f0.y + f1.y) + (f2.y + f3.y);
  }
  for (; i < d; ++i){
    int s = eidx[beg + i];
    float2 u = uph(inp[(size_t)s*64 + lane]);
    a0 += u.x; a1 += u.y;
  }
  out[(size_t)gw*64 + lane] = pkh(a0, a1);
}

// ---------------- MFMA helpers ----------------
// A frag: row = lane&15, k = (lane>>4)*8 + j ; D: col = lane&15, row = (lane>>4)*4 + r
__device__ __forceinline__ void load_a_glob(const _Float16* __restrict__ t, int rbase,
                                            int wv, int lane, int N,
                                            bf16x8 ah[4], bf16x8 al[4]){
  int row = rbase + wv*16 + (lane & 15); if (row >= N) row = N - 1;
  const _Float16* ap = t + (size_t)row*128 + ((lane>>4)*8);
  #pragma unroll
  for (int kt=0;kt<4;kt++){
    f16x8 v = *reinterpret_cast<const f16x8*>(ap + kt*32);
    split8h(v, ah[kt], al[kt]);
  }
}
// LDS f32 tile with row stride `stride` (in floats)
__device__ __forceinline__ void load_a_lds(const float* base, int lane,
                                           bf16x8 ah[4], bf16x8 al[4], int stride){
  int row = lane & 15, ko = (lane>>4)*8;
  #pragma unroll
  for (int kt=0;kt<4;kt++) split8f(base + row*stride + kt*32 + ko, ah[kt], al[kt]);
}

template<int NCT>
__device__ __forceinline__ void mm_stage3(const bf16x8 ah[4], const bf16x8 al[4],
                                          const unsigned short* __restrict__ wh,
                                          const unsigned short* __restrict__ wl,
                                          int lane, f32x4 acc[NCT]){
  #pragma unroll
  for (int ct=0; ct<NCT; ++ct){
    f32x4 c = {0.f,0.f,0.f,0.f};
    #pragma unroll
    for (int kt=0; kt<4; ++kt){
      int fo = ((kt*NCT + ct)*64 + lane) << 3;
      bf16x8 bh = *reinterpret_cast<const bf16x8*>(wh + fo);
      bf16x8 bl = *reinterpret_cast<const bf16x8*>(wl + fo);
      c = __builtin_amdgcn_mfma_f32_16x16x32_bf16(ah[kt], bh, c, 0, 0, 0);
      c = __builtin_amdgcn_mfma_f32_16x16x32_bf16(al[kt], bh, c, 0, 0, 0);
      c = __builtin_amdgcn_mfma_f32_16x16x32_bf16(ah[kt], bl, c, 0, 0, 0);
    }
    acc[ct] = c;
  }
}

// bias + relu -> f32 LDS tile (row stride `stride` floats)
template<int NCT>
__device__ __forceinline__ void epi_relu_lds(const f32x4 acc[NCT], const float* __restrict__ bias,
                                             float* dst, int lane, int stride){
  int r0 = (lane>>4)*4, col0 = lane & 15;
  #pragma unroll
  for (int ct=0; ct<NCT; ++ct){
    float bv = bias[ct*16 + col0];
    #pragma unroll
    for (int r=0;r<4;r++){
      float v = fmaxf(acc[ct][r] + bv, 0.f);
      dst[(r0 + r)*stride + ct*16 + col0] = v;
    }
  }
}

static constexpr int LSTR = 132;   // f32 row stride in LDS (pad 4, 16B aligned)

// ---------------- layer-1 MLP: h1 = relu(relu(t@w1+b1)@w2+b2), fp16 out ----------------
__global__ __launch_bounds__(256) void k_mlp1(const _Float16* __restrict__ t,
    const unsigned short* __restrict__ w1h, const unsigned short* __restrict__ w1l, const float* __restrict__ b1,
    const unsigned short* __restrict__ w2h, const unsigned short* __restrict__ w2l, const float* __restrict__ b2,
    unsigned* __restrict__ h, int N){
  __shared__ float lds[64*LSTR];
  int tid = threadIdx.x, lane = tid & 63, wv = tid >> 6;
  int rbase = blockIdx.x * 64;
  bf16x8 ah[4], al[4];
  f32x4 acc[8];
  load_a_glob(t, rbase, wv, lane, N, ah, al);
  mm_stage3<8>(ah, al, w1h, w1l, lane, acc);
  epi_relu_lds<8>(acc, b1, lds + wv*16*LSTR, lane, LSTR);
  __syncthreads();
  load_a_lds(lds + wv*16*LSTR, lane, ah, al, LSTR);
  __syncthreads();
  mm_stage3<8>(ah, al, w2h, w2l, lane, acc);
  epi_relu_lds<8>(acc, b2, lds + wv*16*LSTR, lane, LSTR);
  __syncthreads();
  int nvalid = N - rbase; if (nvalid > 64) nvalid = 64;
  uint2* dv = reinterpret_cast<uint2*>(h + (size_t)rbase*64);
  for (int i=tid; i < nvalid*32; i += 256){
    int row = i >> 5, c4 = i & 31;
    const float4 f = *reinterpret_cast<const float4*>(&lds[row*LSTR + c4*4]);
    uint2 o; o.x = pkh(f.x, f.y); o.y = pkh(f.z, f.w);
    dv[i] = o;
  }
}

// ------------- layer-2 MLP + head fused: out = sigmoid(mlp_head(relu(mlp2(t2)))) -------------
__global__ __launch_bounds__(256) void k_mlp2_head(const _Float16* __restrict__ t,
    const unsigned short* __restrict__ w1h, const unsigned short* __restrict__ w1l, const float* __restrict__ b1,
    const unsigned short* __restrict__ w2h, const unsigned short* __restrict__ w2l, const float* __restrict__ b2,
    const unsigned short* __restrict__ w3h, const unsigned short* __restrict__ w3l, const float* __restrict__ b3,
    const unsigned short* __restrict__ w4h, const unsigned short* __restrict__ w4l, const float* __restrict__ b4,
    float* __restrict__ out, int N){
  __shared__ float lds[64*LSTR];
  int tid = threadIdx.x, lane = tid & 63, wv = tid >> 6;
  int rbase = blockIdx.x * 64;
  bf16x8 ah[4], al[4];
  f32x4 acc[8];
  // stage1: u2 = relu(t@w21+b21)
  load_a_glob(t, rbase, wv, lane, N, ah, al);
  mm_stage3<8>(ah, al, w1h, w1l, lane, acc);
  epi_relu_lds<8>(acc, b1, lds + wv*16*LSTR, lane, LSTR);
  __syncthreads();
  // stage2: h2 = relu(u2@w22+b22)
  load_a_lds(lds + wv*16*LSTR, lane, ah, al, LSTR);
  __syncthreads();
  mm_stage3<8>(ah, al, w2h, w2l, lane, acc);
  epi_relu_lds<8>(acc, b2, lds + wv*16*LSTR, lane, LSTR);
  __syncthreads();
  // stage3: uh = relu(h2@wm1+bm1)
  load_a_lds(lds + wv*16*LSTR, lane, ah, al, LSTR);
  __syncthreads();
  mm_stage3<8>(ah, al, w3h, w3l, lane, acc);
  epi_relu_lds<8>(acc, b3, lds + wv*16*LSTR, lane, LSTR);
  __syncthreads();
  // stage4: out = sigmoid(uh@wm2+bm2), 64 cols
  load_a_lds(lds + wv*16*LSTR, lane, ah, al, LSTR);
  __syncthreads();
  f32x4 acc4[4];
  mm_stage3<4>(ah, al, w4h, w4l, lane, acc4);
  {
    float* olds = lds;   // reuse as [64][68] f32
    int r0 = (lane>>4)*4, col0 = lane & 15;
    #pragma unroll
    for (int ct=0; ct<4; ++ct){
      float bv = b4[ct*16 + col0];
      #pragma unroll
      for (int r=0;r<4;r++){
        float z = acc4[ct][r] + bv;
        float s = 1.0f / (1.0f + __expf(-z));
        olds[(wv*16 + r0 + r)*68 + ct*16 + col0] = s;
      }
    }
  }
  __syncthreads();
  int nvalid = N - rbase; if (nvalid > 64) nvalid = 64;
  float4* dv = reinterpret_cast<float4*>(out + (size_t)rbase*64);
  for (int i=tid; i < nvalid*16; i += 256){
    int row = i >> 4, c4 = i & 15;
    dv[i] = *reinterpret_cast<const float4*>(&lds[row*68 + c4*4]);
  }
}

// ---------------- host launch ----------------
extern "C" void kernel_launch(void* const* d_in, const int* in_sizes, int n_in,
                              void* d_out, int out_size, void* d_ws, size_t ws_size,
                              hipStream_t stream) {
  const float* x   = (const float*)d_in[0];
  const int*   src = (const int*)  d_in[1];
  const int*   dst = (const int*)  d_in[2];
  const float* eps1= (const float*)d_in[3];
  const float* eps2= (const float*)d_in[4];
  const float* w11 = (const float*)d_in[5];  const float* b11 = (const float*)d_in[6];
  const float* w12 = (const float*)d_in[7];  const float* b12 = (const float*)d_in[8];
  const float* w21 = (const float*)d_in[9];  const float* b21 = (const float*)d_in[10];
  const float* w22 = (const float*)d_in[11]; const float* b22 = (const float*)d_in[12];
  const float* wm1 = (const float*)d_in[13]; const float* bm1 = (const float*)d_in[14];
  const float* wm2 = (const float*)d_in[15]; const float* bm2 = (const float*)d_in[16];

  char* ws = (char*)d_ws;
  size_t off = 0;
  auto alloc = [&](size_t bytes) -> void* {
    void* p = ws + off;
    off = (off + bytes + 255) & ~(size_t)255;
    return p;
  };
  unsigned* xh  = (unsigned*)alloc((size_t)NN*64*4);   // x as fp16 [N][128]
  unsigned* B0  = (unsigned*)alloc((size_t)NN*64*4);   // agg out fp16 (t1 / t2)
  unsigned* h1h = (unsigned*)alloc((size_t)NN*64*4);   // h1 fp16
  int* eidx = (int*)alloc((size_t)NE*4);
  int* deg  = (int*)alloc((size_t)NN*4);
  int* cur  = (int*)alloc((size_t)NN*4);
  int* rs   = (int*)alloc((size_t)NN*4);
  int* bsum = (int*)alloc((size_t)NB_SCAN*4);
  int* boff = (int*)alloc((size_t)NB_SCAN*4);
  unsigned short* p11h = (unsigned short*)alloc(128*128*2);
  unsigned short* p11l = (unsigned short*)alloc(128*128*2);
  unsigned short* p12h = (unsigned short*)alloc(128*128*2);
  unsigned short* p12l = (unsigned short*)alloc(128*128*2);
  unsigned short* p21h = (unsigned short*)alloc(128*128*2);
  unsigned short* p21l = (unsigned short*)alloc(128*128*2);
  unsigned short* p22h = (unsigned short*)alloc(128*128*2);
  unsigned short* p22l = (unsigned short*)alloc(128*128*2);
  unsigned short* pm1h = (unsigned short*)alloc(128*128*2);
  unsigned short* pm1l = (unsigned short*)alloc(128*128*2);
  unsigned short* pm2h = (unsigned short*)alloc(128*64*2);
  unsigned short* pm2l = (unsigned short*)alloc(128*64*2);
  if (off > ws_size) return;   // visible failure if workspace too small

  hipMemsetAsync(deg, 0, (size_t)NN*4, stream);
  hipMemsetAsync(cur, 0, (size_t)NN*4, stream);

  k_pack<<<176, 64, 0, stream>>>(w11,w12,w21,w22,wm1,wm2,
                                 p11h,p11l,p12h,p12l,p21h,p21l,p22h,p22l,pm1h,pm1l,pm2h,pm2l);
  k_cvt<<<(NN*32 + 255)/256, 256, 0, stream>>>(x, xh, NN*32);
  k_count<<<(NE+255)/256, 256, 0, stream>>>(dst, deg, NE);
  k_bsum<<<NB_SCAN, 256, 0, stream>>>(deg, bsum, NN);
  k_boff<<<1, 64, 0, stream>>>(bsum, boff, NB_SCAN);
  k_scan3<<<NB_SCAN, 256, 0, stream>>>(deg, boff, rs, NN);
  k_fill<<<(NE+255)/256, 256, 0, stream>>>(src, dst, rs, cur, eidx, NE);

  // layer 1
  k_agg<<<(NN+3)/4, 256, 0, stream>>>(xh, B0, eps1, rs, deg, eidx, NN);
  k_mlp1<<<(NN+63)/64, 256, 0, stream>>>((const _Float16*)B0, p11h, p11l, b11,
                                         p12h, p12l, b12, h1h, NN);
  // layer 2 + head
  k_agg<<<(NN+3)/4, 256, 0, stream>>>(h1h, B0, eps2, rs, deg, eidx, NN);
  k_mlp2_head<<<(NN+63)/64, 256, 0, stream>>>((const _Float16*)B0, p21h, p21l, b21,
                                              p22h, p22l, b22, pm1h, pm1l, bm1,
                                              pm2h, pm2l, bm2, (float*)d_out, NN);
}

// Round 4
// 333.781 us; speedup vs baseline: 1.9006x; 1.3732x over previous
//
#include <hip/hip_runtime.h>

static constexpr int NN = 100000;
static constexpr int NE = 1600000;
static constexpr int NBUK = (NN + 255) / 256;        // 391 buckets of 256 nodes
static constexpr int SC_BLOCKS = 400;
static constexpr int SC_CH = NE / SC_BLOCKS;         // 4000 edges per block

typedef __bf16    bf16x8 __attribute__((ext_vector_type(8)));
typedef float     f32x4  __attribute__((ext_vector_type(4)));
typedef _Float16  f16x8  __attribute__((ext_vector_type(8)));

__device__ __forceinline__ unsigned short f2b(float f){
  unsigned u = __builtin_bit_cast(unsigned, f);
  u += 0x7fffu + ((u >> 16) & 1u);          // round-to-nearest-even
  return (unsigned short)(u >> 16);
}
__device__ __forceinline__ float b2f(unsigned short b){
  return __builtin_bit_cast(float, (unsigned)b << 16);
}

// split f32 -> (hi, lo) bf16 pair: v ~= hi + lo with ~16-bit mantissa coverage
__device__ __forceinline__ void split1(float v, __bf16& h, __bf16& l){
  unsigned short hb = f2b(v);
  float hf = b2f(hb);
  h = __builtin_bit_cast(__bf16, hb);
  l = __builtin_bit_cast(__bf16, f2b(v - hf));
}

__device__ __forceinline__ void split8f(const float* __restrict__ p, bf16x8& h, bf16x8& l){
  #pragma unroll
  for (int j=0;j<8;j++){
    __bf16 hh, ll; split1(p[j], hh, ll); h[j] = hh; l[j] = ll;
  }
}
__device__ __forceinline__ void split8h(f16x8 v, bf16x8& h, bf16x8& l){
  #pragma unroll
  for (int j=0;j<8;j++){
    __bf16 hh, ll; split1((float)v[j], hh, ll); h[j] = hh; l[j] = ll;
  }
}

// fp16 pack/unpack (2 elems per 32-bit word)
__device__ __forceinline__ unsigned pkh(float x, float y){
  unsigned short a = __builtin_bit_cast(unsigned short, (_Float16)x);
  unsigned short b = __builtin_bit_cast(unsigned short, (_Float16)y);
  return (unsigned)a | ((unsigned)b << 16);
}
__device__ __forceinline__ float2 uph(unsigned u){
  _Float16 a = __builtin_bit_cast(_Float16, (unsigned short)(u & 0xffffu));
  _Float16 b = __builtin_bit_cast(_Float16, (unsigned short)(u >> 16));
  return make_float2((float)a, (float)b);
}

// ---------------- weight packing into MFMA B-fragment order (hi + lo) ----------------
__global__ void k_pack(const float* __restrict__ w11, const float* __restrict__ w12,
                       const float* __restrict__ w21, const float* __restrict__ w22,
                       const float* __restrict__ wm1, const float* __restrict__ wm2,
                       unsigned short* __restrict__ p11h, unsigned short* __restrict__ p11l,
                       unsigned short* __restrict__ p12h, unsigned short* __restrict__ p12l,
                       unsigned short* __restrict__ p21h, unsigned short* __restrict__ p21l,
                       unsigned short* __restrict__ p22h, unsigned short* __restrict__ p22l,
                       unsigned short* __restrict__ pm1h, unsigned short* __restrict__ pm1l,
                       unsigned short* __restrict__ pm2h, unsigned short* __restrict__ pm2l){
  int b = blockIdx.x, lane = threadIdx.x;
  const float* W; unsigned short* Ph; unsigned short* Pl; int NCT, f;
  if (b < 160){
    int m = b >> 5; f = b & 31; NCT = 8;
    W  = (m==0)?w11 :(m==1)?w12 :(m==2)?w21 :(m==3)?w22 :wm1;
    Ph = (m==0)?p11h:(m==1)?p12h:(m==2)?p21h:(m==3)?p22h:pm1h;
    Pl = (m==0)?p11l:(m==1)?p12l:(m==2)?p21l:(m==3)?p22l:pm1l;
  } else { f = b - 160; NCT = 4; W = wm2; Ph = pm2h; Pl = pm2l; }
  int NC = NCT * 16;
  int kt = f / NCT, ct = f % NCT;
  int k0 = kt*32 + ((lane>>4)*8), col = ct*16 + (lane&15);
  unsigned short* dh = Ph + ((size_t)(f*64 + lane))*8;
  unsigned short* dl = Pl + ((size_t)(f*64 + lane))*8;
  #pragma unroll
  for (int j=0;j<8;j++){
    float v = W[(size_t)(k0+j)*NC + col];
    unsigned short hb = f2b(v);
    dh[j] = hb;
    dl[j] = f2b(v - b2f(hb));
  }
}

// ---------------- f32 -> fp16 convert ----------------
__global__ void k_cvt(const float* __restrict__ x, unsigned* __restrict__ xh, int n4){
  int i = blockIdx.x*256 + threadIdx.x;
  if (i < n4){
    float4 v = reinterpret_cast<const float4*>(x)[i];
    uint2 o; o.x = pkh(v.x, v.y); o.y = pkh(v.z, v.w);
    reinterpret_cast<uint2*>(xh)[i] = o;
  }
}

// ---------------- CSR build, bucketed ----------------
__global__ __launch_bounds__(256) void k_hist(const int* __restrict__ dst, int* __restrict__ bhist){
  __shared__ int h[NBUK];
  int blk = blockIdx.x, t = threadIdx.x;
  for (int i=t;i<NBUK;i+=256) h[i]=0;
  __syncthreads();
  int e0 = blk*SC_CH;
  for (int e=e0+t; e<e0+SC_CH; e+=256) atomicAdd(&h[((unsigned)dst[e])>>8], 1);
  __syncthreads();
  for (int i=t;i<NBUK;i+=256){ int c=h[i]; if (c) atomicAdd(&bhist[i], c); }
}

__global__ void k_boff2(const int* __restrict__ bhist, int* __restrict__ boff){
  __shared__ int s[512];
  int t = threadIdx.x;
  int v = (t < NBUK) ? bhist[t] : 0;
  s[t] = v; __syncthreads();
  for (int off=1; off<512; off<<=1){
    int u = 0; if (t>=off) u = s[t-off];
    __syncthreads(); s[t] += u; __syncthreads();
  }
  if (t < NBUK) boff[t] = s[t] - v;   // exclusive prefix
}

__global__ __launch_bounds__(256) void k_scatter1(const int* __restrict__ src,
                                                  const int* __restrict__ dst,
                                                  const int* __restrict__ boff,
                                                  int* __restrict__ gbcur,
                                                  uint2* __restrict__ tmp){
  __shared__ int hc[NBUK];
  __shared__ int hb[NBUK];
  int blk = blockIdx.x, t = threadIdx.x;
  int e0 = blk * SC_CH, e1 = e0 + SC_CH;
  for (int i=t;i<NBUK;i+=256) hc[i]=0;
  __syncthreads();
  for (int e=e0+t; e<e1; e+=256) atomicAdd(&hc[((unsigned)dst[e])>>8], 1);
  __syncthreads();
  for (int i=t;i<NBUK;i+=256){ int c = hc[i]; hb[i] = c ? atomicAdd(&gbcur[i], c) : 0; }
  __syncthreads();
  for (int i=t;i<NBUK;i+=256) hc[i]=0;
  __syncthreads();
  for (int e=e0+t; e<e1; e+=256){
    int d = dst[e]; int b = ((unsigned)d)>>8;
    int pos = atomicAdd(&hc[b], 1);
    tmp[(size_t)boff[b] + hb[b] + pos] = make_uint2((unsigned)src[e], (unsigned)d);
  }
}

// one block per bucket: LDS counting sort -> eidx (sequential writes), emits deg & rs
__global__ __launch_bounds__(256) void k_fill2(const uint2* __restrict__ tmp,
                                               const int* __restrict__ boff,
                                               const int* __restrict__ bhist,
                                               int* __restrict__ eidx,
                                               int* __restrict__ rs, int* __restrict__ deg, int N){
  __shared__ int lh[256];   // per-local-node count
  __shared__ int ls[256];   // inclusive scan
  __shared__ int lc[256];   // placement cursor
  int b = blockIdx.x, t = threadIdx.x;
  int base = boff[b], cnt = bhist[b];
  int nb0 = b*256;
  lh[t] = 0; lc[t] = 0;
  __syncthreads();
  for (int i=t; i<cnt; i+=256) atomicAdd(&lh[(int)tmp[(size_t)base+i].y - nb0], 1);
  __syncthreads();
  int v = lh[t];
  ls[t] = v; __syncthreads();
  for (int off=1; off<256; off<<=1){
    int u = 0; if (t>=off) u = ls[t-off];
    __syncthreads(); ls[t] += u; __syncthreads();
  }
  int node = nb0 + t;
  if (node < N){ deg[node] = v; rs[node] = base + ls[t] - v; }
  __syncthreads();
  for (int i=t; i<cnt; i+=256){
    uint2 e = tmp[(size_t)base+i];
    int local = (int)e.y - nb0;
    int pos = atomicAdd(&lc[local], 1);
    eidx[base + ls[local] - lh[local] + pos] = (int)e.x;
  }
}

// ---- aggregation (fp16 rows, f32 accum): out = (1+eps)*in + sum_{nbr} in[nbr] ----
__global__ __launch_bounds__(256) void k_agg(const unsigned* __restrict__ inp,
                                             unsigned* __restrict__ out,
                                             const float* __restrict__ epsp,
                                             const int* __restrict__ rs, const int* __restrict__ deg,
                                             const int* __restrict__ eidx, int N){
  int gw = (blockIdx.x*256 + threadIdx.x) >> 6;
  int lane = threadIdx.x & 63;
  if (gw >= N) return;
  float sc = 1.0f + *epsp;
  float2 v = uph(inp[(size_t)gw*64 + lane]);
  float a0 = sc * v.x, a1 = sc * v.y;
  int beg = rs[gw], d = deg[gw];
  int i = 0;
  for (; i+8 <= d; i += 8){
    unsigned u[8];
    #pragma unroll
    for (int j=0;j<8;j++) u[j] = inp[(size_t)eidx[beg+i+j]*64 + lane];
    #pragma unroll
    for (int j=0;j<8;j++){ float2 f = uph(u[j]); a0 += f.x; a1 += f.y; }
  }
  for (; i < d; ++i){
    float2 u = uph(inp[(size_t)eidx[beg+i]*64 + lane]);
    a0 += u.x; a1 += u.y;
  }
  out[(size_t)gw*64 + lane] = pkh(a0, a1);
}

// ---------------- MFMA helpers ----------------
// A frag: row = lane&15, k = (lane>>4)*8 + j ; D: col = lane&15, row = (lane>>4)*4 + r
__device__ __forceinline__ void load_a_glob(const _Float16* __restrict__ t, int rbase,
                                            int wv, int lane, int N,
                                            bf16x8 ah[4], bf16x8 al[4]){
  int row = rbase + wv*16 + (lane & 15); if (row >= N) row = N - 1;
  const _Float16* ap = t + (size_t)row*128 + ((lane>>4)*8);
  #pragma unroll
  for (int kt=0;kt<4;kt++){
    f16x8 v = *reinterpret_cast<const f16x8*>(ap + kt*32);
    split8h(v, ah[kt], al[kt]);
  }
}
__device__ __forceinline__ void load_a_lds(const float* base, int lane,
                                           bf16x8 ah[4], bf16x8 al[4], int stride){
  int row = lane & 15, ko = (lane>>4)*8;
  #pragma unroll
  for (int kt=0;kt<4;kt++) split8f(base + row*stride + kt*32 + ko, ah[kt], al[kt]);
}

template<int NCT>
__device__ __forceinline__ void mm_stage3(const bf16x8 ah[4], const bf16x8 al[4],
                                          const unsigned short* __restrict__ wh,
                                          const unsigned short* __restrict__ wl,
                                          int lane, f32x4 acc[NCT]){
  #pragma unroll
  for (int ct=0; ct<NCT; ++ct){
    f32x4 c = {0.f,0.f,0.f,0.f};
    #pragma unroll
    for (int kt=0; kt<4; ++kt){
      int fo = ((kt*NCT + ct)*64 + lane) << 3;
      bf16x8 bh = *reinterpret_cast<const bf16x8*>(wh + fo);
      bf16x8 bl = *reinterpret_cast<const bf16x8*>(wl + fo);
      c = __builtin_amdgcn_mfma_f32_16x16x32_bf16(ah[kt], bh, c, 0, 0, 0);
      c = __builtin_amdgcn_mfma_f32_16x16x32_bf16(al[kt], bh, c, 0, 0, 0);
      c = __builtin_amdgcn_mfma_f32_16x16x32_bf16(ah[kt], bl, c, 0, 0, 0);
    }
    acc[ct] = c;
  }
}

template<int NCT>
__device__ __forceinline__ void epi_relu_lds(const f32x4 acc[NCT], const float* __restrict__ bias,
                                             float* dst, int lane, int stride){
  int r0 = (lane>>4)*4, col0 = lane & 15;
  #pragma unroll
  for (int ct=0; ct<NCT; ++ct){
    float bv = bias[ct*16 + col0];
    #pragma unroll
    for (int r=0;r<4;r++){
      float v = fmaxf(acc[ct][r] + bv, 0.f);
      dst[(r0 + r)*stride + ct*16 + col0] = v;
    }
  }
}

static constexpr int LSTR = 132;   // f32 row stride in LDS (pad 4, 16B aligned)

// ---------------- layer-1 MLP: h1 = relu(relu(t@w1+b1)@w2+b2), fp16 out ----------------
__global__ __launch_bounds__(256) void k_mlp1(const _Float16* __restrict__ t,
    const unsigned short* __restrict__ w1h, const unsigned short* __restrict__ w1l, const float* __restrict__ b1,
    const unsigned short* __restrict__ w2h, const unsigned short* __restrict__ w2l, const float* __restrict__ b2,
    unsigned* __restrict__ h, int N){
  __shared__ float lds[64*LSTR];
  int tid = threadIdx.x, lane = tid & 63, wv = tid >> 6;
  int rbase = blockIdx.x * 64;
  bf16x8 ah[4], al[4];
  f32x4 acc[8];
  load_a_glob(t, rbase, wv, lane, N, ah, al);
  mm_stage3<8>(ah, al, w1h, w1l, lane, acc);
  epi_relu_lds<8>(acc, b1, lds + wv*16*LSTR, lane, LSTR);
  __syncthreads();
  load_a_lds(lds + wv*16*LSTR, lane, ah, al, LSTR);
  __syncthreads();
  mm_stage3<8>(ah, al, w2h, w2l, lane, acc);
  epi_relu_lds<8>(acc, b2, lds + wv*16*LSTR, lane, LSTR);
  __syncthreads();
  int nvalid = N - rbase; if (nvalid > 64) nvalid = 64;
  uint2* dv = reinterpret_cast<uint2*>(h + (size_t)rbase*64);
  for (int i=tid; i < nvalid*32; i += 256){
    int row = i >> 5, c4 = i & 31;
    const float4 f = *reinterpret_cast<const float4*>(&lds[row*LSTR + c4*4]);
    uint2 o; o.x = pkh(f.x, f.y); o.y = pkh(f.z, f.w);
    dv[i] = o;
  }
}

// ------------- layer-2 MLP + head fused: out = sigmoid(mlp_head(relu(mlp2(t2)))) -------------
__global__ __launch_bounds__(256) void k_mlp2_head(const _Float16* __restrict__ t,
    const unsigned short* __restrict__ w1h, const unsigned short* __restrict__ w1l, const float* __restrict__ b1,
    const unsigned short* __restrict__ w2h, const unsigned short* __restrict__ w2l, const float* __restrict__ b2,
    const unsigned short* __restrict__ w3h, const unsigned short* __restrict__ w3l, const float* __restrict__ b3,
    const unsigned short* __restrict__ w4h, const unsigned short* __restrict__ w4l, const float* __restrict__ b4,
    float* __restrict__ out, int N){
  __shared__ float lds[64*LSTR];
  int tid = threadIdx.x, lane = tid & 63, wv = tid >> 6;
  int rbase = blockIdx.x * 64;
  bf16x8 ah[4], al[4];
  f32x4 acc[8];
  load_a_glob(t, rbase, wv, lane, N, ah, al);
  mm_stage3<8>(ah, al, w1h, w1l, lane, acc);
  epi_relu_lds<8>(acc, b1, lds + wv*16*LSTR, lane, LSTR);
  __syncthreads();
  load_a_lds(lds + wv*16*LSTR, lane, ah, al, LSTR);
  __syncthreads();
  mm_stage3<8>(ah, al, w2h, w2l, lane, acc);
  epi_relu_lds<8>(acc, b2, lds + wv*16*LSTR, lane, LSTR);
  __syncthreads();
  load_a_lds(lds + wv*16*LSTR, lane, ah, al, LSTR);
  __syncthreads();
  mm_stage3<8>(ah, al, w3h, w3l, lane, acc);
  epi_relu_lds<8>(acc, b3, lds + wv*16*LSTR, lane, LSTR);
  __syncthreads();
  load_a_lds(lds + wv*16*LSTR, lane, ah, al, LSTR);
  __syncthreads();
  f32x4 acc4[4];
  mm_stage3<4>(ah, al, w4h, w4l, lane, acc4);
  {
    float* olds = lds;   // reuse as [64][68] f32
    int r0 = (lane>>4)*4, col0 = lane & 15;
    #pragma unroll
    for (int ct=0; ct<4; ++ct){
      float bv = b4[ct*16 + col0];
      #pragma unroll
      for (int r=0;r<4;r++){
        float z = acc4[ct][r] + bv;
        float s = 1.0f / (1.0f + __expf(-z));
        olds[(wv*16 + r0 + r)*68 + ct*16 + col0] = s;
      }
    }
  }
  __syncthreads();
  int nvalid = N - rbase; if (nvalid > 64) nvalid = 64;
  float4* dv = reinterpret_cast<float4*>(out + (size_t)rbase*64);
  for (int i=tid; i < nvalid*16; i += 256){
    int row = i >> 4, c4 = i & 15;
    dv[i] = *reinterpret_cast<const float4*>(&lds[row*68 + c4*4]);
  }
}

// ---------------- host launch ----------------
extern "C" void kernel_launch(void* const* d_in, const int* in_sizes, int n_in,
                              void* d_out, int out_size, void* d_ws, size_t ws_size,
                              hipStream_t stream) {
  const float* x   = (const float*)d_in[0];
  const int*   src = (const int*)  d_in[1];
  const int*   dst = (const int*)  d_in[2];
  const float* eps1= (const float*)d_in[3];
  const float* eps2= (const float*)d_in[4];
  const float* w11 = (const float*)d_in[5];  const float* b11 = (const float*)d_in[6];
  const float* w12 = (const float*)d_in[7];  const float* b12 = (const float*)d_in[8];
  const float* w21 = (const float*)d_in[9];  const float* b21 = (const float*)d_in[10];
  const float* w22 = (const float*)d_in[11]; const float* b22 = (const float*)d_in[12];
  const float* wm1 = (const float*)d_in[13]; const float* bm1 = (const float*)d_in[14];
  const float* wm2 = (const float*)d_in[15]; const float* bm2 = (const float*)d_in[16];

  char* ws = (char*)d_ws;
  size_t off = 0;
  auto alloc = [&](size_t bytes) -> void* {
    void* p = ws + off;
    off = (off + bytes + 255) & ~(size_t)255;
    return p;
  };
  unsigned* xh  = (unsigned*)alloc((size_t)NN*64*4);   // x as fp16 [N][128]
  unsigned* B0  = (unsigned*)alloc((size_t)NN*64*4);   // agg out fp16 (t1 / t2)
  unsigned* h1h = (unsigned*)alloc((size_t)NN*64*4);   // h1 fp16
  uint2* tmp = (uint2*)alloc((size_t)NE*8);            // bucketed (src,dst)
  int* eidx = (int*)alloc((size_t)NE*4);
  int* deg  = (int*)alloc((size_t)NN*4);
  int* rs   = (int*)alloc((size_t)NN*4);
  int* bhist= (int*)alloc((size_t)NBUK*4);
  int* boff = (int*)alloc((size_t)NBUK*4);
  int* gbcur= (int*)alloc((size_t)NBUK*4);
  unsigned short* p11h = (unsigned short*)alloc(128*128*2);
  unsigned short* p11l = (unsigned short*)alloc(128*128*2);
  unsigned short* p12h = (unsigned short*)alloc(128*128*2);
  unsigned short* p12l = (unsigned short*)alloc(128*128*2);
  unsigned short* p21h = (unsigned short*)alloc(128*128*2);
  unsigned short* p21l = (unsigned short*)alloc(128*128*2);
  unsigned short* p22h = (unsigned short*)alloc(128*128*2);
  unsigned short* p22l = (unsigned short*)alloc(128*128*2);
  unsigned short* pm1h = (unsigned short*)alloc(128*128*2);
  unsigned short* pm1l = (unsigned short*)alloc(128*128*2);
  unsigned short* pm2h = (unsigned short*)alloc(128*64*2);
  unsigned short* pm2l = (unsigned short*)alloc(128*64*2);
  if (off > ws_size) return;   // visible failure if workspace too small

  hipMemsetAsync(bhist, 0, (size_t)NBUK*4, stream);
  hipMemsetAsync(gbcur, 0, (size_t)NBUK*4, stream);

  k_pack<<<176, 64, 0, stream>>>(w11,w12,w21,w22,wm1,wm2,
                                 p11h,p11l,p12h,p12l,p21h,p21l,p22h,p22l,pm1h,pm1l,pm2h,pm2l);
  k_cvt<<<(NN*32 + 255)/256, 256, 0, stream>>>(x, xh, NN*32);
  k_hist<<<SC_BLOCKS, 256, 0, stream>>>(dst, bhist);
  k_boff2<<<1, 512, 0, stream>>>(bhist, boff);
  k_scatter1<<<SC_BLOCKS, 256, 0, stream>>>(src, dst, boff, gbcur, tmp);
  k_fill2<<<NBUK, 256, 0, stream>>>(tmp, boff, bhist, eidx, rs, deg, NN);

  // layer 1
  k_agg<<<(NN+3)/4, 256, 0, stream>>>(xh, B0, eps1, rs, deg, eidx, NN);
  k_mlp1<<<(NN+63)/64, 256, 0, stream>>>((const _Float16*)B0, p11h, p11l, b11,
                                         p12h, p12l, b12, h1h, NN);
  // layer 2 + head
  k_agg<<<(NN+3)/4, 256, 0, stream>>>(h1h, B0, eps2, rs, deg, eidx, NN);
  k_mlp2_head<<<(NN+63)/64, 256, 0, stream>>>((const _Float16*)B0, p21h, p21l, b21,
                                              p22h, p22l, b22, pm1h, pm1l, bm1,
                                              pm2h, pm2l, bm2, (float*)d_out, NN);
}